// Round 1
// baseline (376.554 us; speedup 1.0000x reference)
//
#include <hip/hip_runtime.h>
#include <math.h>

#define S 16
#define C 8
#define N 5000
#define T 100

// ---------------- Kernel A: state-init + transition log-softmax + HMM forward recursion ----------------
__global__ void hmm_forward_kernel(const float* __restrict__ u_init,
                                   const float* __restrict__ u_T,
                                   float* __restrict__ out_h,   // (T,S) in d_out
                                   float* __restrict__ ws_h) {  // (T,S) scratch copy
    __shared__ float sh_h[S];
    __shared__ float sh_logT[S * S];
    __shared__ float s_lse;
    const int tid = threadIdx.x;

    // log_softmax of state_init (16 values)
    if (tid == 0) {
        float m = -INFINITY;
        for (int i = 0; i < S; ++i) m = fmaxf(m, u_init[i]);
        float s = 0.f;
        for (int i = 0; i < S; ++i) s += expf(u_init[i] - m);
        s_lse = m + logf(s);
    }
    __syncthreads();
    if (tid < S) sh_h[tid] = u_init[tid] - s_lse;

    // row-wise log_softmax of transition matrix: thread i handles row i
    if (tid < S) {
        float m = -INFINITY;
        for (int j = 0; j < S; ++j) m = fmaxf(m, u_T[tid * S + j]);
        float s = 0.f;
        for (int j = 0; j < S; ++j) s += expf(u_T[tid * S + j] - m);
        float lse = m + logf(s);
        for (int j = 0; j < S; ++j) sh_logT[tid * S + j] = u_T[tid * S + j] - lse;
    }
    __syncthreads();

    if (tid < S) {
        out_h[tid] = sh_h[tid];
        ws_h[tid]  = sh_h[tid];
    }
    __syncthreads();

    for (int t = 1; t < T; ++t) {
        float hn = 0.f;
        if (tid < S) {
            float m = -INFINITY;
            for (int i = 0; i < S; ++i) m = fmaxf(m, sh_h[i] + sh_logT[i * S + tid]);
            float s = 0.f;
            for (int i = 0; i < S; ++i) s += expf(sh_h[i] + sh_logT[i * S + tid] - m);
            hn = m + logf(s);
        }
        __syncthreads();
        if (tid < S) {
            sh_h[tid] = hn;
            out_h[t * S + tid] = hn;
            ws_h[t * S + tid]  = hn;
        }
        __syncthreads();
    }
}

// ---------------- Kernel B: emission log-softmax over nodes (axis=1), one block per state ----------------
__global__ void emission_norm_kernel(const float* __restrict__ u_e,
                                     float* __restrict__ ws_le) {  // (S,N)
    const int s = blockIdx.x;
    const int tid = threadIdx.x;
    const float* row = u_e + s * N;
    __shared__ float red[256];

    float m = -INFINITY;
    for (int n = tid; n < N; n += 256) m = fmaxf(m, row[n]);
    red[tid] = m;
    __syncthreads();
    for (int o = 128; o > 0; o >>= 1) {
        if (tid < o) red[tid] = fmaxf(red[tid], red[tid + o]);
        __syncthreads();
    }
    m = red[0];
    __syncthreads();

    float sum = 0.f;
    for (int n = tid; n < N; n += 256) sum += expf(row[n] - m);
    red[tid] = sum;
    __syncthreads();
    for (int o = 128; o > 0; o >>= 1) {
        if (tid < o) red[tid] += red[tid + o];
        __syncthreads();
    }
    const float lse = m + logf(red[0]);

    for (int n = tid; n < N; n += 256) ws_le[s * N + n] = row[n] - lse;
}

// ---------------- Kernel C: chain-weight log-softmax over chains (axis=-1), one thread per node ----------------
__global__ void chain_norm_kernel(const float* __restrict__ u_cw,
                                  float* __restrict__ ws_lcw) {  // (N,C)
    const int n = blockIdx.x * blockDim.x + threadIdx.x;
    if (n >= N) return;
    float v[C];
    float m = -INFINITY;
    for (int c = 0; c < C; ++c) {
        v[c] = u_cw[n * C + c];
        m = fmaxf(m, v[c]);
    }
    float s = 0.f;
    for (int c = 0; c < C; ++c) s += expf(v[c] - m);
    const float lse = m + logf(s);
    for (int c = 0; c < C; ++c) ws_lcw[n * C + c] = v[c] - lse;
}

// ---------------- Kernel D: lwT[s][c][n] = le[s][n] + lcw[n][c]  (transposed log_weights) ----------------
__global__ void build_lwt_kernel(const float* __restrict__ ws_le,
                                 const float* __restrict__ ws_lcw,
                                 float* __restrict__ ws_lwt) {  // (S,C,N)
    const int sc = blockIdx.x;       // s*C + c
    const int s = sc >> 3;
    const int c = sc & 7;
    const float* le = ws_le + s * N;
    float* dst = ws_lwt + sc * N;
    for (int n = threadIdx.x; n < N; n += 256) {
        dst[n] = le[n] + ws_lcw[n * C + c];
    }
}

// ---------------- Kernel E: out0[t][n] = logsumexp_s(h[t][s] + le[s][n])  (chains sum to 1) ----------------
__global__ void out0_kernel(const float* __restrict__ ws_le,
                            const float* __restrict__ ws_h,
                            float* __restrict__ out0) {  // (T,N)
    const int t = blockIdx.x;
    __shared__ float h[S];
    if (threadIdx.x < S) h[threadIdx.x] = ws_h[t * S + threadIdx.x];
    __syncthreads();
    for (int n = threadIdx.x; n < N; n += 256) {
        float v[S];
        float m = -INFINITY;
        for (int s = 0; s < S; ++s) {
            v[s] = h[s] + ws_le[s * N + n];
            m = fmaxf(m, v[s]);
        }
        float sum = 0.f;
        for (int s = 0; s < S; ++s) sum += expf(v[s] - m);
        out0[t * N + n] = m + logf(sum);
    }
}

// ---------------- Kernel F: the 256 MB broadcast-add write: out_perm[t][s][c][n] = lwT[s][c][n] + h[t][s] ----------------
__global__ __launch_bounds__(256) void perm_kernel(const float4* __restrict__ ws_lwt4,
                                                   const float* __restrict__ ws_h,
                                                   float4* __restrict__ out4) {
    const int slice = blockIdx.x;      // t*(S*C) + s*C + c
    const int sc = slice & (S * C - 1);
    const int t = slice >> 7;          // / (S*C)
    const int s = sc >> 3;
    const float hval = ws_h[t * S + s];

    const float4* __restrict__ src = ws_lwt4 + sc * (N / 4);
    float4* __restrict__ dst = out4 + (size_t)slice * (N / 4);

    for (int i = threadIdx.x; i < N / 4; i += 256) {
        float4 v = src[i];
        v.x += hval; v.y += hval; v.z += hval; v.w += hval;
        dst[i] = v;
    }
}

extern "C" void kernel_launch(void* const* d_in, const int* in_sizes, int n_in,
                              void* d_out, int out_size, void* d_ws, size_t ws_size,
                              hipStream_t stream) {
    const float* u_init = (const float*)d_in[0];   // (S,)
    const float* u_cw   = (const float*)d_in[1];   // (1,N,C)
    const float* u_e    = (const float*)d_in[2];   // (S,N)
    const float* u_T    = (const float*)d_in[3];   // (S,S)

    float* out = (float*)d_out;
    float* out0     = out;                                   // (T,N)      500000
    float* out_perm = out + (size_t)T * N;                   // (T,S,C,N)  64000000
    float* out_h    = out + (size_t)T * N + (size_t)T * S * C * N;  // (T,S) 1600

    float* ws  = (float*)d_ws;
    float* ws_h   = ws;                  // 1600
    float* ws_le  = ws + 1600;           // 80000
    float* ws_lcw = ws + 1600 + 80000;   // 40000
    float* ws_lwt = ws + 1600 + 80000 + 40000;  // 640000 (16B-aligned: offset 486400 B)

    hmm_forward_kernel<<<1, 64, 0, stream>>>(u_init, u_T, out_h, ws_h);
    emission_norm_kernel<<<S, 256, 0, stream>>>(u_e, ws_le);
    chain_norm_kernel<<<(N + 255) / 256, 256, 0, stream>>>(u_cw, ws_lcw);
    build_lwt_kernel<<<S * C, 256, 0, stream>>>(ws_le, ws_lcw, ws_lwt);
    out0_kernel<<<T, 256, 0, stream>>>(ws_le, ws_h, out0);
    perm_kernel<<<T * S * C, 256, 0, stream>>>((const float4*)ws_lwt, ws_h, (float4*)out_perm);
}

// Round 2
// 284.689 us; speedup vs baseline: 1.3227x; 1.3227x over previous
//
#include <hip/hip_runtime.h>
#include <math.h>

#define S 16
#define C 8
#define N 5000
#define T 100
#define N4 1250   // N / 4 float4 columns

// ---------------- Prep kernel ----------------
// blocks 0..15  : emission log-softmax over nodes (row s = blockIdx.x)
// blocks 16..35 : chain log-softmax over chains (256 nodes per block)
// block  36     : HMM forward recursion in linear space (single wave, no barriers)
__global__ __launch_bounds__(256) void prep_kernel(const float* __restrict__ u_init,
                                                   const float* __restrict__ u_cw,
                                                   const float* __restrict__ u_e,
                                                   const float* __restrict__ u_T,
                                                   float* __restrict__ ws_le,   // (S,N)
                                                   float* __restrict__ ws_lcw,  // (N,C)
                                                   float* __restrict__ ws_h,    // (T,S)
                                                   float* __restrict__ out_h) { // (T,S)
    const int b = blockIdx.x;
    const int tid = threadIdx.x;

    if (b < 16) {
        // ---- emission row log-softmax ----
        const float* row = u_e + b * N;
        __shared__ float red[256];
        float m = -INFINITY;
        for (int n = tid; n < N; n += 256) m = fmaxf(m, row[n]);
        red[tid] = m;
        __syncthreads();
        for (int o = 128; o > 0; o >>= 1) {
            if (tid < o) red[tid] = fmaxf(red[tid], red[tid + o]);
            __syncthreads();
        }
        m = red[0];
        __syncthreads();
        float sum = 0.f;
        for (int n = tid; n < N; n += 256) sum += expf(row[n] - m);
        red[tid] = sum;
        __syncthreads();
        for (int o = 128; o > 0; o >>= 1) {
            if (tid < o) red[tid] += red[tid + o];
            __syncthreads();
        }
        const float lse = m + logf(red[0]);
        for (int n = tid; n < N; n += 256) ws_le[b * N + n] = row[n] - lse;
    } else if (b < 36) {
        // ---- chain log-softmax ----
        const int n = (b - 16) * 256 + tid;
        if (n < N) {
            float v[C];
            float m = -INFINITY;
            for (int c = 0; c < C; ++c) {
                v[c] = u_cw[n * C + c];
                m = fmaxf(m, v[c]);
            }
            float s = 0.f;
            for (int c = 0; c < C; ++c) s += expf(v[c] - m);
            const float lse = m + logf(s);
            for (int c = 0; c < C; ++c) ws_lcw[n * C + c] = v[c] - lse;
        }
    } else {
        // ---- HMM forward recursion, linear space, single wave ----
        if (tid < S) {
            const int j = tid;
            // log-softmax of state init
            float m = -INFINITY;
            for (int i = 0; i < S; ++i) m = fmaxf(m, u_init[i]);
            float ssum = 0.f;
            for (int i = 0; i < S; ++i) ssum += expf(u_init[i] - m);
            const float lse0 = m + logf(ssum);
            const float h0 = u_init[j] - lse0;
            out_h[j] = h0;
            ws_h[j] = h0;
            // row-softmax of transition: thread j computes lse of row j
            float mr = -INFINITY;
            for (int k = 0; k < S; ++k) mr = fmaxf(mr, u_T[j * S + k]);
            float sr = 0.f;
            for (int k = 0; k < S; ++k) sr += expf(u_T[j * S + k] - mr);
            const float lse_row = mr + logf(sr);
            // thread j holds column j of Texp: Texp[i][j] = exp(u_T[i][j] - lse_i)
            float texp[S];
            #pragma unroll
            for (int i = 0; i < S; ++i) {
                const float lse_i = __shfl(lse_row, i, 64);
                texp[i] = expf(u_T[i * S + j] - lse_i);
            }
            // p_{t+1}[j] = sum_i p_t[i] * Texp[i][j]; h_t = log(p_t)
            float p = expf(h0);
            for (int t = 1; t < T; ++t) {
                float pn = 0.f;
                #pragma unroll
                for (int i = 0; i < S; ++i) {
                    pn = fmaf(__shfl(p, i, 64), texp[i], pn);
                }
                p = pn;
                const float hv = logf(p);
                out_h[t * S + j] = hv;
                ws_h[t * S + j] = hv;
            }
        }
    }
}

// ---------------- Main fused kernel ----------------
// grid (5 chunks, T). Each thread owns one float4 column group (4 nodes) for one t.
// Writes out_perm[t][s][c][n] = le[s][n] + h[t][s] + lcw[n][c]  (128 float4 stores)
// and   out0[t][n] = logsumexp_s(le[s][n] + h[t][s])            (1 float4 store)
__global__ __launch_bounds__(256) void main_kernel(const float* __restrict__ ws_le,
                                                   const float* __restrict__ ws_lcw,
                                                   const float* __restrict__ ws_h,
                                                   float* __restrict__ out0,
                                                   float* __restrict__ out_perm) {
    const int t = blockIdx.y;
    const int i = blockIdx.x * 256 + threadIdx.x;  // float4 column index, 0..1249

    __shared__ float h[S];
    if (threadIdx.x < S) h[threadIdx.x] = ws_h[t * S + threadIdx.x];
    __syncthreads();
    if (i >= N4) return;

    // load chain weights for our 4 nodes: lc[c][k] = lcw[4i+k][c] (32 contiguous floats)
    float lc[C][4];
    const float4* __restrict__ lcw4 = (const float4*)ws_lcw;
    #pragma unroll
    for (int j = 0; j < 8; ++j) {
        const float4 v = lcw4[8 * (size_t)i + j];
        const int nl = j >> 1;
        const int cb = (j & 1) * 4;
        lc[cb + 0][nl] = v.x;
        lc[cb + 1][nl] = v.y;
        lc[cb + 2][nl] = v.z;
        lc[cb + 3][nl] = v.w;
    }

    const float4* __restrict__ le4 = (const float4*)ws_le;
    float4* __restrict__ outp4 = (float4*)out_perm;

    float4 a[S];
    float4 m4 = make_float4(-INFINITY, -INFINITY, -INFINITY, -INFINITY);

    #pragma unroll
    for (int s = 0; s < S; ++s) {
        const float4 e = le4[(size_t)s * N4 + i];
        const float hs = h[s];
        a[s].x = e.x + hs; a[s].y = e.y + hs; a[s].z = e.z + hs; a[s].w = e.w + hs;
        m4.x = fmaxf(m4.x, a[s].x); m4.y = fmaxf(m4.y, a[s].y);
        m4.z = fmaxf(m4.z, a[s].z); m4.w = fmaxf(m4.w, a[s].w);
        const size_t base = (((size_t)t * S + s) * C) * N4 + i;
        #pragma unroll
        for (int c = 0; c < C; ++c) {
            float4 w;
            w.x = a[s].x + lc[c][0];
            w.y = a[s].y + lc[c][1];
            w.z = a[s].z + lc[c][2];
            w.w = a[s].w + lc[c][3];
            outp4[base + (size_t)c * N4] = w;
        }
    }

    float4 sum4 = make_float4(0.f, 0.f, 0.f, 0.f);
    #pragma unroll
    for (int s = 0; s < S; ++s) {
        sum4.x += expf(a[s].x - m4.x);
        sum4.y += expf(a[s].y - m4.y);
        sum4.z += expf(a[s].z - m4.z);
        sum4.w += expf(a[s].w - m4.w);
    }
    float4 r;
    r.x = m4.x + logf(sum4.x);
    r.y = m4.y + logf(sum4.y);
    r.z = m4.z + logf(sum4.z);
    r.w = m4.w + logf(sum4.w);
    ((float4*)out0)[(size_t)t * N4 + i] = r;
}

extern "C" void kernel_launch(void* const* d_in, const int* in_sizes, int n_in,
                              void* d_out, int out_size, void* d_ws, size_t ws_size,
                              hipStream_t stream) {
    const float* u_init = (const float*)d_in[0];   // (S,)
    const float* u_cw   = (const float*)d_in[1];   // (1,N,C)
    const float* u_e    = (const float*)d_in[2];   // (S,N)
    const float* u_T    = (const float*)d_in[3];   // (S,S)

    float* out = (float*)d_out;
    float* out0     = out;                                          // (T,N)
    float* out_perm = out + (size_t)T * N;                          // (T,S,C,N)
    float* out_h    = out + (size_t)T * N + (size_t)T * S * C * N;  // (T,S)

    float* ws  = (float*)d_ws;
    float* ws_h   = ws;                   // 1600 floats
    float* ws_le  = ws + 1600;            // 80000 floats (offset 6400 B, 16B-aligned)
    float* ws_lcw = ws + 1600 + 80000;    // 40000 floats (offset 326400 B, 16B-aligned)

    prep_kernel<<<37, 256, 0, stream>>>(u_init, u_cw, u_e, u_T, ws_le, ws_lcw, ws_h, out_h);
    main_kernel<<<dim3(5, T), 256, 0, stream>>>(ws_le, ws_lcw, ws_h, out0, out_perm);
}